// Round 14
// baseline (122.677 us; speedup 1.0000x reference)
//
#include <hip/hip_runtime.h>
#include <math.h>

// Problem constants
constexpr int B_   = 32;
constexpr int G_   = 8;
constexpr int CIN  = 64;
constexpr int CAPS = 4;
constexpr int OUTC = 64;
constexpr int HID  = 512;           // CIN * RATIO
constexpr int CO   = CAPS * OUTC;   // 256
constexpr int HW   = 64 * 64;       // 4096

typedef float __attribute__((ext_vector_type(4))) f32x4;

// ---------------------------------------------------------------------------
// K1: pool. 2048 blocks x 256 threads (8 blocks/CU, 32 waves/CU).
// R14 experiment: CACHED loads (was NT in R9-R13) to decompose the R9 win.
// ---------------------------------------------------------------------------
__global__ __launch_bounds__(256) void pool_kernel(const float* __restrict__ emb,
                                                   float* __restrict__ pooled) {
    const int bid = blockIdx.x, tid = threadIdx.x;
    const int lane = tid & 63, wave = tid >> 6;
    const int ch0 = bid * 8 + wave * 2;     // 2048 blocks * 8 ch = 16384
    const float4* p0 = reinterpret_cast<const float4*>(emb) + (size_t)ch0 * (HW / 4);
    const float4* p1 = p0 + (HW / 4);
    float s0 = 0.f, s1 = 0.f;
    #pragma unroll
    for (int k = 0; k < 16; ++k) {
        float4 v = p0[lane + k * 64];
        s0 += v.x + v.y + v.z + v.w;
    }
    #pragma unroll
    for (int k = 0; k < 16; ++k) {
        float4 v = p1[lane + k * 64];
        s1 += v.x + v.y + v.z + v.w;
    }
    #pragma unroll
    for (int off = 32; off; off >>= 1) {
        s0 += __shfl_down(s0, off);
        s1 += __shfl_down(s1, off);
    }
    if (lane == 0) {
        pooled[ch0]     = s0 * (1.0f / HW);
        pooled[ch0 + 1] = s1 * (1.0f / HW);
    }
}

// ---------------------------------------------------------------------------
// K2: fc. 256 blocks = (b,g); weights served from L2/LLC across 256 CUs.
// (verified R9 — do NOT reduce block count, R10 showed -50us)
// ---------------------------------------------------------------------------
__global__ __launch_bounds__(256) void fc_kernel(const float* __restrict__ pooled,
                                                 const float* __restrict__ w1,
                                                 const float* __restrict__ b1,
                                                 const float* __restrict__ w2,
                                                 const float* __restrict__ b2,
                                                 float* __restrict__ atts) {
    const int bg = blockIdx.x;
    const int g = bg % G_;
    __shared__ float pin[CIN];
    __shared__ float h[HID];
    const int t = threadIdx.x;
    if (t < CIN) pin[t] = pooled[(size_t)bg * CIN + t];
    __syncthreads();

    const float* W1 = w1 + (size_t)g * HID * CIN;
    for (int o = t; o < HID; o += 256) {
        const float4* wrow = reinterpret_cast<const float4*>(W1 + (size_t)o * CIN);
        float acc = b1[g * HID + o];
        #pragma unroll
        for (int i = 0; i < CIN / 4; ++i) {
            float4 w = wrow[i];
            acc += w.x * pin[4 * i] + w.y * pin[4 * i + 1] +
                   w.z * pin[4 * i + 2] + w.w * pin[4 * i + 3];
        }
        h[o] = fmaxf(acc, 0.f);
    }
    __syncthreads();

    {
        const int o = t;  // 256 threads == CO outputs
        const float* W2 = w2 + (size_t)g * CO * HID;
        const float4* wrow = reinterpret_cast<const float4*>(W2 + (size_t)o * HID);
        float acc = b2[g * CO + o];
        #pragma unroll 8
        for (int i = 0; i < HID / 4; ++i) {
            float4 w = wrow[i];
            acc += w.x * h[4 * i] + w.y * h[4 * i + 1] +
                   w.z * h[4 * i + 2] + w.w * h[4 * i + 3];
        }
        atts[(size_t)bg * CO + o] = acc;
    }
}

// ---------------------------------------------------------------------------
// K3: route_scale. 2048 blocks; block = (batch b = bid>>6, slice = bid&63).
// Redundant per-block routing (R11-verified); NT load+store on x/out.
// ---------------------------------------------------------------------------
__global__ __launch_bounds__(256) void route_scale(const float* __restrict__ x,
                                                   const float* __restrict__ atts,
                                                   float* __restrict__ out) {
    const int bid = blockIdx.x, tid = threadIdx.x;
    const int b = bid >> 6;           // batch
    const int slice = bid & 63;       // 4-channel slice within batch

    __shared__ float xr[G_ * CAPS * OUTC];   // 2048
    __shared__ float beta[G_ * CAPS];
    __shared__ float alpha[G_ * CAPS];
    __shared__ float vv[CAPS * OUTC];        // 256
    __shared__ float nrm[CAPS];

    for (int i = tid; i < G_ * CAPS * OUTC; i += 256)
        xr[i] = atts[(size_t)b * G_ * CO + i];
    if (tid < G_ * CAPS) beta[tid] = 0.f;
    __syncthreads();

    for (int iter = 0; iter < 3; ++iter) {
        if (tid < G_ * CAPS) {
            const int g = tid / CAPS;
            float m = fmaxf(fmaxf(beta[g * CAPS + 0], beta[g * CAPS + 1]),
                            fmaxf(beta[g * CAPS + 2], beta[g * CAPS + 3]));
            float se = 0.f;
            #pragma unroll
            for (int c = 0; c < CAPS; ++c) se += expf(beta[g * CAPS + c] - m);
            alpha[tid] = expf(beta[tid] - m) / se;
        }
        __syncthreads();
        {
            const int c = tid >> 6;
            float acc = 0.f;
            #pragma unroll
            for (int g = 0; g < G_; ++g)
                acc += alpha[g * CAPS + c] * xr[(g * CAPS + c) * OUTC + (tid & 63)];
            vv[tid] = acc;
        }
        __syncthreads();
        if (iter < 2) {
            float sq = vv[tid] * vv[tid];
            #pragma unroll
            for (int off = 32; off; off >>= 1) sq += __shfl_down(sq, off);
            if ((tid & 63) == 0) nrm[tid >> 6] = sqrtf(sq);
            __syncthreads();
            if (tid < G_ * CAPS) {
                const int g = tid / CAPS, c = tid % CAPS;
                const float inv = 1.f / fmaxf(nrm[c], 1e-12f);
                float acc = 0.f;
                #pragma unroll
                for (int o = 0; o < OUTC; ++o)
                    acc += vv[c * OUTC + o] * xr[(g * CAPS + c) * OUTC + o];
                beta[tid] += acc * inv;
            }
            __syncthreads();
        }
    }
    // vv holds routed (pre-sigmoid) for this batch.

    const int c0 = slice * 4;
    #pragma unroll
    for (int c = 0; c < 4; ++c) {
        const float s = 1.f / (1.f + expf(-vv[c0 + c]));   // block-uniform
        const int ch = b * CO + c0 + c;
        const f32x4* xi = reinterpret_cast<const f32x4*>(x) + (size_t)ch * (HW / 4);
        f32x4* oo = reinterpret_cast<f32x4*>(out) + (size_t)ch * (HW / 4);
        #pragma unroll
        for (int k = 0; k < 4; ++k) {
            f32x4 v = __builtin_nontemporal_load(&xi[tid + k * 256]);
            v.x *= s; v.y *= s; v.z *= s; v.w *= s;
            __builtin_nontemporal_store(v, &oo[tid + k * 256]);
        }
    }
}

extern "C" void kernel_launch(void* const* d_in, const int* in_sizes, int n_in,
                              void* d_out, int out_size, void* d_ws, size_t ws_size,
                              hipStream_t stream) {
    const float* emb = (const float*)d_in[0];
    const float* x   = (const float*)d_in[1];
    const float* w1  = (const float*)d_in[2];
    const float* b1  = (const float*)d_in[3];
    const float* w2  = (const float*)d_in[4];
    const float* b2  = (const float*)d_in[5];
    float* out = (float*)d_out;

    float* wsf    = (float*)d_ws;
    float* pooled = wsf;                      // 16384
    float* atts   = wsf + 16384;              // 65536

    pool_kernel<<<2048, 256, 0, stream>>>(emb, pooled);
    fc_kernel<<<B_ * G_, 256, 0, stream>>>(pooled, w1, b1, w2, b2, atts);
    route_scale<<<2048, 256, 0, stream>>>(x, atts, out);
}

// Round 18
// 119.192 us; speedup vs baseline: 1.0292x; 1.0292x over previous
//
#include <hip/hip_runtime.h>
#include <math.h>

// Problem constants
constexpr int B_   = 32;
constexpr int G_   = 8;
constexpr int CIN  = 64;
constexpr int CAPS = 4;
constexpr int OUTC = 64;
constexpr int HID  = 512;           // CIN * RATIO
constexpr int CO   = CAPS * OUTC;   // 256
constexpr int HW   = 64 * 64;       // 4096

typedef float __attribute__((ext_vector_type(4))) f32x4;

// ---------------------------------------------------------------------------
// K1: pool. 2048 blocks x 256 threads. NT loads (R14: NT worth ~2us on reads).
// Explicit 8-deep load batches to raise in-flight bytes per wave
// (latency-hiding arithmetic: need ~9KB/CU in flight; was ~3KB at VGPR=44).
// ---------------------------------------------------------------------------
__global__ __launch_bounds__(256) void pool_kernel(const float* __restrict__ emb,
                                                   float* __restrict__ pooled) {
    const int bid = blockIdx.x, tid = threadIdx.x;
    const int lane = tid & 63, wave = tid >> 6;
    const int ch0 = bid * 8 + wave * 2;     // 2048 blocks * 8 ch = 16384
    const f32x4* p0 = reinterpret_cast<const f32x4*>(emb) + (size_t)ch0 * (HW / 4);
    const f32x4* p1 = p0 + (HW / 4);
    float s0 = 0.f, s1 = 0.f;
    f32x4 r[8];
    #pragma unroll
    for (int h = 0; h < 2; ++h) {
        #pragma unroll
        for (int j = 0; j < 8; ++j)
            r[j] = __builtin_nontemporal_load(&p0[lane + (h * 8 + j) * 64]);
        #pragma unroll
        for (int j = 0; j < 8; ++j)
            s0 += r[j].x + r[j].y + r[j].z + r[j].w;
    }
    #pragma unroll
    for (int h = 0; h < 2; ++h) {
        #pragma unroll
        for (int j = 0; j < 8; ++j)
            r[j] = __builtin_nontemporal_load(&p1[lane + (h * 8 + j) * 64]);
        #pragma unroll
        for (int j = 0; j < 8; ++j)
            s1 += r[j].x + r[j].y + r[j].z + r[j].w;
    }
    #pragma unroll
    for (int off = 32; off; off >>= 1) {
        s0 += __shfl_down(s0, off);
        s1 += __shfl_down(s1, off);
    }
    if (lane == 0) {
        pooled[ch0]     = s0 * (1.0f / HW);
        pooled[ch0 + 1] = s1 * (1.0f / HW);
    }
}

// ---------------------------------------------------------------------------
// K2: fc. 256 blocks = (b,g); weights served from L2/LLC across 256 CUs.
// (verified R9 — do NOT reduce block count, R10 showed -50us)
// ---------------------------------------------------------------------------
__global__ __launch_bounds__(256) void fc_kernel(const float* __restrict__ pooled,
                                                 const float* __restrict__ w1,
                                                 const float* __restrict__ b1,
                                                 const float* __restrict__ w2,
                                                 const float* __restrict__ b2,
                                                 float* __restrict__ atts) {
    const int bg = blockIdx.x;
    const int g = bg % G_;
    __shared__ float pin[CIN];
    __shared__ float h[HID];
    const int t = threadIdx.x;
    if (t < CIN) pin[t] = pooled[(size_t)bg * CIN + t];
    __syncthreads();

    const float* W1 = w1 + (size_t)g * HID * CIN;
    for (int o = t; o < HID; o += 256) {
        const float4* wrow = reinterpret_cast<const float4*>(W1 + (size_t)o * CIN);
        float acc = b1[g * HID + o];
        #pragma unroll
        for (int i = 0; i < CIN / 4; ++i) {
            float4 w = wrow[i];
            acc += w.x * pin[4 * i] + w.y * pin[4 * i + 1] +
                   w.z * pin[4 * i + 2] + w.w * pin[4 * i + 3];
        }
        h[o] = fmaxf(acc, 0.f);
    }
    __syncthreads();

    {
        const int o = t;  // 256 threads == CO outputs
        const float* W2 = w2 + (size_t)g * CO * HID;
        const float4* wrow = reinterpret_cast<const float4*>(W2 + (size_t)o * HID);
        float acc = b2[g * CO + o];
        #pragma unroll 8
        for (int i = 0; i < HID / 4; ++i) {
            float4 w = wrow[i];
            acc += w.x * h[4 * i] + w.y * h[4 * i + 1] +
                   w.z * h[4 * i + 2] + w.w * h[4 * i + 3];
        }
        atts[(size_t)bg * CO + o] = acc;
    }
}

// ---------------------------------------------------------------------------
// K3: route_scale. 2048 blocks; block = (batch, 4-ch slice). Redundant
// routing (R11). Streaming loop k-outer with 8 NT loads in flight
// (4 channels x 2 k-steps) before the 8 scale+stores.
// ---------------------------------------------------------------------------
__global__ __launch_bounds__(256) void route_scale(const float* __restrict__ x,
                                                   const float* __restrict__ atts,
                                                   float* __restrict__ out) {
    const int bid = blockIdx.x, tid = threadIdx.x;
    const int b = bid >> 6;           // batch
    const int slice = bid & 63;       // 4-channel slice within batch

    __shared__ float xr[G_ * CAPS * OUTC];   // 2048
    __shared__ float beta[G_ * CAPS];
    __shared__ float alpha[G_ * CAPS];
    __shared__ float vv[CAPS * OUTC];        // 256
    __shared__ float nrm[CAPS];

    for (int i = tid; i < G_ * CAPS * OUTC; i += 256)
        xr[i] = atts[(size_t)b * G_ * CO + i];
    if (tid < G_ * CAPS) beta[tid] = 0.f;
    __syncthreads();

    for (int iter = 0; iter < 3; ++iter) {
        if (tid < G_ * CAPS) {
            const int g = tid / CAPS;
            float m = fmaxf(fmaxf(beta[g * CAPS + 0], beta[g * CAPS + 1]),
                            fmaxf(beta[g * CAPS + 2], beta[g * CAPS + 3]));
            float se = 0.f;
            #pragma unroll
            for (int c = 0; c < CAPS; ++c) se += expf(beta[g * CAPS + c] - m);
            alpha[tid] = expf(beta[tid] - m) / se;
        }
        __syncthreads();
        {
            const int c = tid >> 6;
            float acc = 0.f;
            #pragma unroll
            for (int g = 0; g < G_; ++g)
                acc += alpha[g * CAPS + c] * xr[(g * CAPS + c) * OUTC + (tid & 63)];
            vv[tid] = acc;
        }
        __syncthreads();
        if (iter < 2) {
            float sq = vv[tid] * vv[tid];
            #pragma unroll
            for (int off = 32; off; off >>= 1) sq += __shfl_down(sq, off);
            if ((tid & 63) == 0) nrm[tid >> 6] = sqrtf(sq);
            __syncthreads();
            if (tid < G_ * CAPS) {
                const int g = tid / CAPS, c = tid % CAPS;
                const float inv = 1.f / fmaxf(nrm[c], 1e-12f);
                float acc = 0.f;
                #pragma unroll
                for (int o = 0; o < OUTC; ++o)
                    acc += vv[c * OUTC + o] * xr[(g * CAPS + c) * OUTC + o];
                beta[tid] += acc * inv;
            }
            __syncthreads();
        }
    }
    // vv holds routed (pre-sigmoid) for this batch.

    const int c0 = slice * 4;
    const int ch_base = b * CO + c0;
    float sc[4];
    #pragma unroll
    for (int c = 0; c < 4; ++c)
        sc[c] = 1.f / (1.f + expf(-vv[c0 + c]));

    const f32x4* xi = reinterpret_cast<const f32x4*>(x) + (size_t)ch_base * (HW / 4);
    f32x4* oo = reinterpret_cast<f32x4*>(out) + (size_t)ch_base * (HW / 4);

    #pragma unroll
    for (int k2 = 0; k2 < 2; ++k2) {
        f32x4 r[8];
        #pragma unroll
        for (int c = 0; c < 4; ++c)
            #pragma unroll
            for (int j = 0; j < 2; ++j)
                r[c * 2 + j] = __builtin_nontemporal_load(
                    &xi[(size_t)c * (HW / 4) + tid + (k2 * 2 + j) * 256]);
        #pragma unroll
        for (int c = 0; c < 4; ++c)
            #pragma unroll
            for (int j = 0; j < 2; ++j) {
                f32x4 v = r[c * 2 + j];
                const float s = sc[c];
                v.x *= s; v.y *= s; v.z *= s; v.w *= s;
                __builtin_nontemporal_store(v,
                    &oo[(size_t)c * (HW / 4) + tid + (k2 * 2 + j) * 256]);
            }
    }
}

extern "C" void kernel_launch(void* const* d_in, const int* in_sizes, int n_in,
                              void* d_out, int out_size, void* d_ws, size_t ws_size,
                              hipStream_t stream) {
    const float* emb = (const float*)d_in[0];
    const float* x   = (const float*)d_in[1];
    const float* w1  = (const float*)d_in[2];
    const float* b1  = (const float*)d_in[3];
    const float* w2  = (const float*)d_in[4];
    const float* b2  = (const float*)d_in[5];
    float* out = (float*)d_out;

    float* wsf    = (float*)d_ws;
    float* pooled = wsf;                      // 16384
    float* atts   = wsf + 16384;              // 65536

    pool_kernel<<<2048, 256, 0, stream>>>(emb, pooled);
    fc_kernel<<<B_ * G_, 256, 0, stream>>>(pooled, w1, b1, w2, b2, atts);
    route_scale<<<2048, 256, 0, stream>>>(x, atts, out);
}